// Round 5
// baseline (1016.884 us; speedup 1.0000x reference)
//
#include <hip/hip_runtime.h>

typedef unsigned short u16;
typedef __attribute__((ext_vector_type(4))) float f32x4;
typedef __attribute__((ext_vector_type(4))) unsigned short u16x4;
typedef __attribute__((ext_vector_type(8))) short s16x8;

#define DEV __device__ __forceinline__

DEV float bf2f(u16 h) { union { unsigned u; float f; } x; x.u = ((unsigned)h) << 16; return x.f; }
DEV u16 f2bf(float f) {
  union { float f; unsigned u; } x; x.f = f;
  unsigned r = x.u + 0x7fffu + ((x.u >> 16) & 1u);
  return (u16)(r >> 16);
}

DEV void async_copy16(u16* lds_dst, const u16* g_src) {
  __builtin_amdgcn_global_load_lds(
      (const __attribute__((address_space(1))) unsigned int*)g_src,
      (__attribute__((address_space(3))) unsigned int*)lds_dst, 16, 0, 0);
}

// ---------------------------------------------------------------------------
__global__ __launch_bounds__(256) void cvt_f32_bf16(const float* __restrict__ in,
                                                    u16* __restrict__ out, int n4) {
  int i = blockIdx.x * 256 + threadIdx.x;
  if (i < n4) {
    f32x4 v = ((const f32x4*)in)[i];
    u16x4 o;
    o.x = f2bf(v.x); o.y = f2bf(v.y); o.z = f2bf(v.z); o.w = f2bf(v.w);
    ((u16x4*)out)[i] = o;
  }
}

// ---------------------------------------------------------------------------
// Interleave Wc/Wcg rows into B': B'[2n]=Wc[n], B'[2n+1]=Wcg[n] (bf16).
__global__ __launch_bounds__(256) void cvt_interleave(const float* __restrict__ wc,
                                                      const float* __restrict__ wcg,
                                                      u16* __restrict__ out) {
  const int i = blockIdx.x * 256 + threadIdx.x;  // over 16384*1024/4
  const int n = i >> 8, k4 = i & 255;
  f32x4 a = ((const f32x4*)wc)[i];
  f32x4 b = ((const f32x4*)wcg)[i];
  u16x4 oa, ob;
  oa.x = f2bf(a.x); oa.y = f2bf(a.y); oa.z = f2bf(a.z); oa.w = f2bf(a.w);
  ob.x = f2bf(b.x); ob.y = f2bf(b.y); ob.z = f2bf(b.z); ob.w = f2bf(b.w);
  ((u16x4*)out)[(size_t)(2 * n) * 256 + k4] = oa;
  ((u16x4*)out)[(size_t)(2 * n + 1) * 256 + k4] = ob;
}

// ---------------------------------------------------------------------------
// LayerNorm over D=1024, one block per token. in/outF may alias (same-thread r->w).
__global__ __launch_bounds__(256) void ln_kernel(const float* in,
                                                 const float* __restrict__ g,
                                                 const float* __restrict__ be,
                                                 u16* __restrict__ out,
                                                 float* outF) {
  const int t = blockIdx.x;
  const int tid = threadIdx.x;
  __shared__ float red[16];
  f32x4 v = ((const f32x4*)(in + (size_t)t * 1024))[tid];
  float s  = v.x + v.y + v.z + v.w;
  float s2 = v.x * v.x + v.y * v.y + v.z * v.z + v.w * v.w;
#pragma unroll
  for (int o = 1; o < 64; o <<= 1) { s += __shfl_xor(s, o); s2 += __shfl_xor(s2, o); }
  const int w = tid >> 6, lane = tid & 63;
  if (lane == 0) { red[w] = s; red[8 + w] = s2; }
  __syncthreads();
  s  = red[0] + red[1] + red[2] + red[3];
  s2 = red[8] + red[9] + red[10] + red[11];
  const float mean = s * (1.f / 1024.f);
  const float rst  = rsqrtf(s2 * (1.f / 1024.f) - mean * mean + 1e-5f);
  f32x4 gv  = ((const f32x4*)g)[tid];
  f32x4 bev = ((const f32x4*)be)[tid];
  f32x4 y;
  y.x = (v.x - mean) * rst * gv.x + bev.x;
  y.y = (v.y - mean) * rst * gv.y + bev.y;
  y.z = (v.z - mean) * rst * gv.z + bev.z;
  y.w = (v.w - mean) * rst * gv.w + bev.w;
  u16x4 o;
  o.x = f2bf(y.x); o.y = f2bf(y.y); o.z = f2bf(y.z); o.w = f2bf(y.w);
  ((u16x4*)out)[(size_t)t * 256 + tid] = o;
  if (outF) ((f32x4*)(outF + (size_t)t * 1024))[tid] = y;
}

// ---------------------------------------------------------------------------
__global__ __launch_bounds__(256) void bproj_kernel(
    const float* __restrict__ bv, const float* __restrict__ g1, const float* __restrict__ be1,
    const float* __restrict__ Wb, const float* __restrict__ bb,
    const float* __restrict__ Wbg, const float* __restrict__ bbg,
    float* __restrict__ bg_tr) {
  const int t = blockIdx.x;
  const int tid = threadIdx.x;
  __shared__ float xs[1024];
  __shared__ float red[16];
  f32x4 v = ((const f32x4*)(bv + (size_t)t * 1024))[tid];
  float s  = v.x + v.y + v.z + v.w;
  float s2 = v.x * v.x + v.y * v.y + v.z * v.z + v.w * v.w;
#pragma unroll
  for (int o = 1; o < 64; o <<= 1) { s += __shfl_xor(s, o); s2 += __shfl_xor(s2, o); }
  const int w = tid >> 6, lane = tid & 63;
  if (lane == 0) { red[w] = s; red[8 + w] = s2; }
  __syncthreads();
  s  = red[0] + red[1] + red[2] + red[3];
  s2 = red[8] + red[9] + red[10] + red[11];
  const float mean = s * (1.f / 1024.f);
  const float rst  = rsqrtf(s2 * (1.f / 1024.f) - mean * mean + 1e-5f);
  f32x4 gv  = ((const f32x4*)g1)[tid];
  f32x4 bev = ((const f32x4*)be1)[tid];
  f32x4 y;
  y.x = (v.x - mean) * rst * gv.x + bev.x;
  y.y = (v.y - mean) * rst * gv.y + bev.y;
  y.z = (v.z - mean) * rst * gv.z + bev.z;
  y.w = (v.w - mean) * rst * gv.w + bev.w;
  ((f32x4*)xs)[tid] = y;
  __syncthreads();
  const int h = tid >> 4, c = tid & 15;
  const float* wb  = Wb + h * 1024;
  const float* wbg = Wbg + h * 1024;
  float p = 0.f, pg = 0.f;
  for (int i = c; i < 1024; i += 16) {
    float xv = xs[i];
    p += xv * wb[i];
    pg += xv * wbg[i];
  }
#pragma unroll
  for (int o = 1; o < 16; o <<= 1) { p += __shfl_xor(p, o); pg += __shfl_xor(pg, o); }
  if (c == 0) {
    float gate = 1.f / (1.f + expf(-(pg + bbg[h])));
    bg_tr[(((t >> 10) * 16 + h)) * 1024 + (t & 1023)] = (p + bb[h]) * gate;
  }
}

// ---------------------------------------------------------------------------
__global__ void scan_kernel(const float* __restrict__ bg_tr, const float* __restrict__ A,
                            const float* __restrict__ h0, float* __restrict__ hs,
                            float* __restrict__ lasth) {
  const int i = threadIdx.x;  // 0..63
  const int b = i >> 4, h = i & 15;
  const float delta = expf(A[h]);
  float hv = h0[b * 16 + h];
  const float* src = bg_tr + (size_t)i * 1024;
  for (int l = 0; l < 1024; l += 4) {
    f32x4 bx = *(const f32x4*)(src + l);
    hv = delta * hv + bx.x; hs[((size_t)(b << 10) + l + 0) * 16 + h] = hv;
    hv = delta * hv + bx.y; hs[((size_t)(b << 10) + l + 1) * 16 + h] = hv;
    hv = delta * hv + bx.z; hs[((size_t)(b << 10) + l + 2) * 16 + h] = hv;
    hv = delta * hv + bx.w; hs[((size_t)(b << 10) + l + 3) * 16 + h] = hv;
  }
  lasth[b * 16 + h] = hv;
}

// ---------------------------------------------------------------------------
// 256x256x64 dbuf GEMM, 8 waves (2m x 4n), T2 swizzle, issue-early/wait-late.
// EPI 1: interleaved-gate epilogue -> bf16 (even cols = value, odd = gate)
// EPI 2: gelu(acc+bias) -> bf16
template <int EPI>
__global__ __launch_bounds__(512, 1) void gemm256(
    const u16* __restrict__ A, const u16* __restrict__ B,
    const float* __restrict__ bias0, const float* __restrict__ bias1,
    u16* __restrict__ outB, int GX, int Nreal, int K) {
  __shared__ u16 lds[2][2][256 * 64];  // [buf][A/B][row*64+col], 128 KB

  const int tid = threadIdx.x;
  const int lane = tid & 63;
  const int wid = tid >> 6;
  const int wm = wid >> 2, wn = wid & 3;  // 2 x 4 wave grid
  const int r16 = lane & 15, kg = lane >> 4;
  const int swz = (r16 & 7) << 4;  // byte-XOR for swizzled ds_read

  // XCD-aware block swizzle (nwg divisible by 8 for all our launches)
  const int nwg = gridDim.x;
  const int q8 = nwg >> 3;
  const int wg = ((int)blockIdx.x & 7) * q8 + ((int)blockIdx.x >> 3);
  const int mt = wg % GX, nt = wg / GX;
  const size_t rowA = (size_t)mt * 256, rowB = (size_t)nt * 256;

  // staging source offsets (u16 units); inverse-swizzled global source (rule 21)
  unsigned offA[4], offB[4];
#pragma unroll
  for (int s4 = 0; s4 < 4; ++s4) {
    const int s = tid + s4 * 512;
    const int row = s >> 3;
    const int kc = (s & 7) ^ (row & 7);
    offA[s4] = (unsigned)((rowA + row) * K + kc * 8);
    offB[s4] = (unsigned)((rowB + row) * K + kc * 8);
  }

  auto stage = [&](int b) {
#pragma unroll
    for (int s4 = 0; s4 < 4; ++s4) {
      const int s = tid + s4 * 512;
      async_copy16(&lds[b][0][s * 8], A + offA[s4]);
      async_copy16(&lds[b][1][s * 8], B + offB[s4]);
      offA[s4] += 64; offB[s4] += 64;
    }
  };

  auto rd = [&](int b, int mat, int rowbase, int kh) -> s16x8 {
    const int byte = (rowbase + r16) * 128 + ((kh * 64 + kg * 16) ^ swz);
    return *(const s16x8*)((const char*)&lds[b][mat][0] + byte);
  };

  f32x4 acc[8][4] = {};
  stage(0);
  asm volatile("s_waitcnt vmcnt(0)" ::: "memory");
  __builtin_amdgcn_s_barrier();

  const int NT = K >> 6;
  int p = 0;
  const int am = wm * 128;
  const int bn = wn * 64;
  for (int t = 0; t < NT; ++t) {
    if (t + 1 < NT) stage(p ^ 1);  // issue-early: 8 loads for next tile
    s16x8 af[8], bfr[8];
    // ph0: A rows mi0-3, B cols ni0-1
#pragma unroll
    for (int mi = 0; mi < 4; ++mi)
#pragma unroll
      for (int kh = 0; kh < 2; ++kh) af[mi * 2 + kh] = rd(p, 0, am + mi * 16, kh);
#pragma unroll
    for (int ni = 0; ni < 2; ++ni)
#pragma unroll
      for (int kh = 0; kh < 2; ++kh) bfr[ni * 2 + kh] = rd(p, 1, bn + ni * 16, kh);
    __builtin_amdgcn_s_setprio(1);
#pragma unroll
    for (int mi = 0; mi < 4; ++mi)
#pragma unroll
      for (int ni = 0; ni < 2; ++ni)
#pragma unroll
        for (int kh = 0; kh < 2; ++kh)
          acc[mi][ni] = __builtin_amdgcn_mfma_f32_16x16x32_bf16(af[mi * 2 + kh], bfr[ni * 2 + kh],
                                                                acc[mi][ni], 0, 0, 0);
    __builtin_amdgcn_s_setprio(0);
    // ph1: B cols ni2-3 (A reused)
#pragma unroll
    for (int ni = 0; ni < 2; ++ni)
#pragma unroll
      for (int kh = 0; kh < 2; ++kh) bfr[4 + ni * 2 + kh] = rd(p, 1, bn + (2 + ni) * 16, kh);
    __builtin_amdgcn_s_setprio(1);
#pragma unroll
    for (int mi = 0; mi < 4; ++mi)
#pragma unroll
      for (int ni = 0; ni < 2; ++ni)
#pragma unroll
        for (int kh = 0; kh < 2; ++kh)
          acc[mi][2 + ni] = __builtin_amdgcn_mfma_f32_16x16x32_bf16(
              af[mi * 2 + kh], bfr[4 + ni * 2 + kh], acc[mi][2 + ni], 0, 0, 0);
    __builtin_amdgcn_s_setprio(0);
    __builtin_amdgcn_sched_barrier(0);  // split register lifetimes (af reuse)
    // ph2: A rows mi4-7 (B ni2-3 reused)
#pragma unroll
    for (int mi = 0; mi < 4; ++mi)
#pragma unroll
      for (int kh = 0; kh < 2; ++kh) af[mi * 2 + kh] = rd(p, 0, am + (4 + mi) * 16, kh);
    __builtin_amdgcn_s_setprio(1);
#pragma unroll
    for (int mi = 0; mi < 4; ++mi)
#pragma unroll
      for (int ni = 0; ni < 2; ++ni)
#pragma unroll
        for (int kh = 0; kh < 2; ++kh)
          acc[4 + mi][2 + ni] = __builtin_amdgcn_mfma_f32_16x16x32_bf16(
              af[mi * 2 + kh], bfr[4 + ni * 2 + kh], acc[4 + mi][2 + ni], 0, 0, 0);
    // ph3: all reused
#pragma unroll
    for (int mi = 0; mi < 4; ++mi)
#pragma unroll
      for (int ni = 0; ni < 2; ++ni)
#pragma unroll
        for (int kh = 0; kh < 2; ++kh)
          acc[4 + mi][ni] = __builtin_amdgcn_mfma_f32_16x16x32_bf16(
              af[mi * 2 + kh], bfr[ni * 2 + kh], acc[4 + mi][ni], 0, 0, 0);
    __builtin_amdgcn_s_setprio(0);
    // wait-late: loads had ~64 MFMAs to complete
    asm volatile("s_waitcnt vmcnt(0)" ::: "memory");
    __builtin_amdgcn_s_barrier();
    p ^= 1;
  }

  // epilogue
#pragma unroll
  for (int mi = 0; mi < 8; ++mi)
#pragma unroll
    for (int ni = 0; ni < 4; ++ni) {
      const int ncol = nt * 256 + wn * 64 + ni * 16 + r16;
      const int grow0 = (int)rowA + wm * 128 + mi * 16 + kg * 4;
      if constexpr (EPI == 1) {
        const int nreal = ncol >> 1;
        const float b0 = bias0[nreal];
        const float b1 = bias1[nreal];
#pragma unroll
        for (int j = 0; j < 4; ++j) {
          const float v = acc[mi][ni][j];
          const float g = __shfl_xor(v, 1);
          if (!(lane & 1)) {
            const float vv = v + b0;
            const float vg = g + b1;
            outB[(size_t)(grow0 + j) * Nreal + nreal] = f2bf(vv / (1.f + expf(-vg)));
          }
        }
      } else {
        const float b0 = bias0[ncol];
#pragma unroll
        for (int j = 0; j < 4; ++j) {
          const float v = acc[mi][ni][j] + b0;
          outB[(size_t)(grow0 + j) * Nreal + ncol] =
              f2bf(0.5f * v * (1.f + erff(v * 0.70710678118654752f)));
        }
      }
    }
}

// ---------------------------------------------------------------------------
// contract: u[t,o] = bv[t,o] + u_in[t,o](=Dout) + sum_h hs[t,h]*cg[t,h*1024+o]
__global__ __launch_bounds__(256) void contract_kernel(
    const float* __restrict__ bv, const u16* __restrict__ cg,
    const float* __restrict__ hs, float* u) {
  const int t = blockIdx.x;
  const int tid = threadIdx.x;
  __shared__ float hsl[16];
  if (tid < 16) hsl[tid] = hs[(size_t)t * 16 + tid];
  __syncthreads();
  f32x4 acc = ((const f32x4*)(bv + (size_t)t * 1024))[tid];
  f32x4 dv = ((f32x4*)(u + (size_t)t * 1024))[tid];
  acc += dv;
  const u16* cgrow = cg + (size_t)t * 16384;
#pragma unroll
  for (int h = 0; h < 16; ++h) {
    float s = hsl[h];
    u16x4 cv = *(const u16x4*)(cgrow + h * 1024 + tid * 4);
    acc.x += s * bf2f(cv.x);
    acc.y += s * bf2f(cv.y);
    acc.z += s * bf2f(cv.z);
    acc.w += s * bf2f(cv.w);
  }
  ((f32x4*)(u + (size_t)t * 1024))[tid] = acc;
}

// ---------------------------------------------------------------------------
// Plain GEMM: wave tile 64x64, WM x WN waves. EPI: 0=+bias->f32; 3=+bias+residF->f32.
// outF/residF may alias (same-thread r->w).
template <int WM, int WN, int EPI>
__global__ __launch_bounds__(WM * WN * 64, 2) void gemm_t(
    const u16* __restrict__ A, const u16* __restrict__ B0, const float* __restrict__ bias0,
    float* outF, const float* residF, int N, int K) {
  constexpr int BM = WM * 64, BN = WN * 64, BK = 32, T = WM * WN * 64;
  __shared__ u16 lds_a[BM * BK];
  __shared__ u16 lds_b[BN * BK];
  const int tid = threadIdx.x;
  const int lane = tid & 63;
  const int w = tid >> 6;
  const int wm = w % WM, wn = w / WM;
  const int row16 = lane & 15, kg = lane >> 4;
  const size_t rowA = (size_t)blockIdx.x * BM;
  const size_t rowB = (size_t)blockIdx.y * BN;
  f32x4 acc[4][4] = {};

  for (int k0 = 0; k0 < K; k0 += BK) {
#pragma unroll
    for (int s = 0; s < BM * 4 / T; ++s) {
      const int slot = s * T + tid;
      async_copy16(&lds_a[slot * 8], A + (rowA + (slot >> 2)) * K + k0 + ((slot & 3) << 3));
    }
#pragma unroll
    for (int s = 0; s < BN * 4 / T; ++s) {
      const int slot = s * T + tid;
      async_copy16(&lds_b[slot * 8], B0 + (rowB + (slot >> 2)) * K + k0 + ((slot & 3) << 3));
    }
    __syncthreads();

    s16x8 af[4], bfr[4];
#pragma unroll
    for (int i = 0; i < 4; ++i)
      af[i] = *(const s16x8*)&lds_a[(wm * 64 + i * 16 + row16) * BK + kg * 8];
#pragma unroll
    for (int i = 0; i < 4; ++i)
      bfr[i] = *(const s16x8*)&lds_b[(wn * 64 + i * 16 + row16) * BK + kg * 8];
#pragma unroll
    for (int mi = 0; mi < 4; ++mi)
#pragma unroll
      for (int ni = 0; ni < 4; ++ni)
        acc[mi][ni] = __builtin_amdgcn_mfma_f32_16x16x32_bf16(af[mi], bfr[ni], acc[mi][ni], 0, 0, 0);
    __syncthreads();
  }

  const int mbase = (int)rowA + wm * 64;
  const int nbase = (int)rowB + wn * 64;
#pragma unroll
  for (int mi = 0; mi < 4; ++mi) {
#pragma unroll
    for (int ni = 0; ni < 4; ++ni) {
      const int col = nbase + ni * 16 + row16;
      const float b0 = bias0[col];
#pragma unroll
      for (int j = 0; j < 4; ++j) {
        const int rrow = mbase + mi * 16 + kg * 4 + j;
        const size_t idx = (size_t)rrow * N + col;
        const float v = acc[mi][ni][j] + b0;
        if constexpr (EPI == 0) {
          outF[idx] = v;
        } else {
          outF[idx] = v + residF[idx];
        }
      }
    }
  }
}

// ---------------------------------------------------------------------------
extern "C" void kernel_launch(void* const* d_in, const int* in_sizes, int n_in,
                              void* d_out, int out_size, void* d_ws, size_t ws_size,
                              hipStream_t stream) {
  const float* bv   = (const float*)d_in[0];
  const float* h0   = (const float*)d_in[1];
  const float* Aarr = (const float*)d_in[2];
  const float* Wb   = (const float*)d_in[3];
  const float* bb   = (const float*)d_in[4];
  const float* Wc   = (const float*)d_in[5];
  const float* bc   = (const float*)d_in[6];
  const float* Wd   = (const float*)d_in[7];
  const float* bd   = (const float*)d_in[8];
  const float* Wbg  = (const float*)d_in[9];
  const float* bbg  = (const float*)d_in[10];
  const float* Wcg  = (const float*)d_in[11];
  const float* bcg  = (const float*)d_in[12];
  const float* W1   = (const float*)d_in[13];
  const float* b1   = (const float*)d_in[14];
  const float* W2   = (const float*)d_in[15];
  const float* b2   = (const float*)d_in[16];
  const float* g1   = (const float*)d_in[17];
  const float* be1  = (const float*)d_in[18];
  const float* g2   = (const float*)d_in[19];
  const float* be2  = (const float*)d_in[20];

  float* out = (float*)d_out;
  float* out_lasth = out + (size_t)4096 * 1024;
  float* u_buf = out;  // u / Dout / y2-f32 live in d_out until FFN2 overwrites

  char* p = (char*)d_ws;
  auto take = [&](size_t bytes) -> char* {
    char* r = p;
    p += (bytes + 255) & ~(size_t)255;
    return r;
  };
  u16* wci_bf  = (u16*)take((size_t)32768 * 1024 * 2);  // 64 MB (interleaved Wc/Wcg)
  u16* wd_bf   = (u16*)take((size_t)1024 * 1024 * 2);   //  2 MB
  u16* w1_bf   = (u16*)take((size_t)4096 * 1024 * 2);   //  8 MB
  u16* w2_bf   = (u16*)take((size_t)1024 * 4096 * 2);   //  8 MB
  u16* x_bf    = (u16*)take((size_t)4096 * 1024 * 2);   //  8 MB
  float* bg_tr = (float*)take((size_t)64 * 1024 * 4);   // .25 MB
  float* hs    = (float*)take((size_t)4096 * 16 * 4);   // .25 MB
  u16* cg_bf   = (u16*)take((size_t)4096 * 16384 * 2);  // 128 MB
  const size_t need = (size_t)(p - (char*)d_ws);        // ~218.5 MB (ran in R4)
  if (ws_size < need) return;

  // buffers live only after gemm256<1> is done with wci -> alias onto it
  u16* f1_bf = wci_bf;                             // 32 MB
  u16* y2_bf = wci_bf + (size_t)16384 * 1024;      //  8 MB (offset 32 MB)

  // 1. weight conversions
  cvt_interleave<<<16384, 256, 0, stream>>>(Wc, Wcg, wci_bf);
  cvt_f32_bf16<<<1024, 256, 0, stream>>>(Wd, wd_bf, 1024 * 1024 / 4);
  cvt_f32_bf16<<<4096, 256, 0, stream>>>(W1, w1_bf, 4096 * 1024 / 4);
  cvt_f32_bf16<<<4096, 256, 0, stream>>>(W2, w2_bf, 1024 * 4096 / 4);

  // 2. LN1 -> x_bf16
  ln_kernel<<<4096, 256, 0, stream>>>(bv, g1, be1, x_bf, nullptr);

  // 3. gated B projection (own f32 LN, exact) -> bg_tr
  bproj_kernel<<<4096, 256, 0, stream>>>(bv, g1, be1, Wb, bb, Wbg, bbg, bg_tr);

  // 4. scan -> hs, last_h
  scan_kernel<<<1, 64, 0, stream>>>(bg_tr, Aarr, h0, hs, out_lasth);

  // 5a. gated C GEMM via interleaved B' (N'=32768) -> cg_bf (4096 x 16384)
  gemm256<1><<<2048, 512, 0, stream>>>(x_bf, wci_bf, bc, bcg, cg_bf, 16, 16384, 1024);

  // 5b. Dout -> u_buf (d_out)
  gemm_t<2, 2, 0><<<dim3(32, 8), 256, 0, stream>>>(x_bf, wd_bf, bd, u_buf, nullptr, 1024, 1024);

  // 5c. u = bv + Dout + sum_h hs*cg   (in-place on u_buf)
  contract_kernel<<<4096, 256, 0, stream>>>(bv, cg_bf, hs, u_buf);

  // 6. LN2 -> y2_bf16 (+ f32 y2 in-place into u_buf)
  ln_kernel<<<4096, 256, 0, stream>>>(u_buf, g2, be2, y2_bf, u_buf);

  // 7. FFN1 exact-erf GELU -> f1_bf (4096 x 4096)
  gemm256<2><<<256, 512, 0, stream>>>(y2_bf, w1_bf, b1, nullptr, f1_bf, 16, 4096, 1024);

  // 8. FFN2 + bias + residual(y2 f32) -> d_out
  gemm_t<2, 2, 3><<<dim3(32, 8), 256, 0, stream>>>(f1_bf, w2_bf, b2, out, u_buf, 1024, 4096);
}

// Round 8
// 869.683 us; speedup vs baseline: 1.1693x; 1.1693x over previous
//
#include <hip/hip_runtime.h>

typedef unsigned short u16;
typedef __attribute__((ext_vector_type(4))) float f32x4;
typedef __attribute__((ext_vector_type(4))) unsigned short u16x4;
typedef __attribute__((ext_vector_type(8))) short s16x8;

#define DEV __device__ __forceinline__

DEV float bf2f(u16 h) { union { unsigned u; float f; } x; x.u = ((unsigned)h) << 16; return x.f; }
DEV u16 f2bf(float f) {
  union { float f; unsigned u; } x; x.f = f;
  unsigned r = x.u + 0x7fffu + ((x.u >> 16) & 1u);
  return (u16)(r >> 16);
}

DEV void async_copy16(u16* lds_dst, const u16* g_src) {
  __builtin_amdgcn_global_load_lds(
      (const __attribute__((address_space(1))) unsigned int*)g_src,
      (__attribute__((address_space(3))) unsigned int*)lds_dst, 16, 0, 0);
}

// ---------------------------------------------------------------------------
__global__ __launch_bounds__(256) void cvt_f32_bf16(const float* __restrict__ in,
                                                    u16* __restrict__ out, int n4) {
  int i = blockIdx.x * 256 + threadIdx.x;
  if (i < n4) {
    f32x4 v = ((const f32x4*)in)[i];
    u16x4 o;
    o.x = f2bf(v.x); o.y = f2bf(v.y); o.z = f2bf(v.z); o.w = f2bf(v.w);
    ((u16x4*)out)[i] = o;
  }
}

// ---------------------------------------------------------------------------
// LayerNorm over D=1024, one block per token. in/outF may alias (same-thread r->w).
__global__ __launch_bounds__(256) void ln_kernel(const float* in,
                                                 const float* __restrict__ g,
                                                 const float* __restrict__ be,
                                                 u16* __restrict__ out,
                                                 float* outF) {
  const int t = blockIdx.x;
  const int tid = threadIdx.x;
  __shared__ float red[16];
  f32x4 v = ((const f32x4*)(in + (size_t)t * 1024))[tid];
  float s  = v.x + v.y + v.z + v.w;
  float s2 = v.x * v.x + v.y * v.y + v.z * v.z + v.w * v.w;
#pragma unroll
  for (int o = 1; o < 64; o <<= 1) { s += __shfl_xor(s, o); s2 += __shfl_xor(s2, o); }
  const int w = tid >> 6, lane = tid & 63;
  if (lane == 0) { red[w] = s; red[8 + w] = s2; }
  __syncthreads();
  s  = red[0] + red[1] + red[2] + red[3];
  s2 = red[8] + red[9] + red[10] + red[11];
  const float mean = s * (1.f / 1024.f);
  const float rst  = rsqrtf(s2 * (1.f / 1024.f) - mean * mean + 1e-5f);
  f32x4 gv  = ((const f32x4*)g)[tid];
  f32x4 bev = ((const f32x4*)be)[tid];
  f32x4 y;
  y.x = (v.x - mean) * rst * gv.x + bev.x;
  y.y = (v.y - mean) * rst * gv.y + bev.y;
  y.z = (v.z - mean) * rst * gv.z + bev.z;
  y.w = (v.w - mean) * rst * gv.w + bev.w;
  u16x4 o;
  o.x = f2bf(y.x); o.y = f2bf(y.y); o.z = f2bf(y.z); o.w = f2bf(y.w);
  ((u16x4*)out)[(size_t)t * 256 + tid] = o;
  if (outF) ((f32x4*)(outF + (size_t)t * 1024))[tid] = y;
}

// ---------------------------------------------------------------------------
__global__ __launch_bounds__(256) void bproj_kernel(
    const float* __restrict__ bv, const float* __restrict__ g1, const float* __restrict__ be1,
    const float* __restrict__ Wb, const float* __restrict__ bb,
    const float* __restrict__ Wbg, const float* __restrict__ bbg,
    float* __restrict__ bg_tr) {
  const int t = blockIdx.x;
  const int tid = threadIdx.x;
  __shared__ float xs[1024];
  __shared__ float red[16];
  f32x4 v = ((const f32x4*)(bv + (size_t)t * 1024))[tid];
  float s  = v.x + v.y + v.z + v.w;
  float s2 = v.x * v.x + v.y * v.y + v.z * v.z + v.w * v.w;
#pragma unroll
  for (int o = 1; o < 64; o <<= 1) { s += __shfl_xor(s, o); s2 += __shfl_xor(s2, o); }
  const int w = tid >> 6, lane = tid & 63;
  if (lane == 0) { red[w] = s; red[8 + w] = s2; }
  __syncthreads();
  s  = red[0] + red[1] + red[2] + red[3];
  s2 = red[8] + red[9] + red[10] + red[11];
  const float mean = s * (1.f / 1024.f);
  const float rst  = rsqrtf(s2 * (1.f / 1024.f) - mean * mean + 1e-5f);
  f32x4 gv  = ((const f32x4*)g1)[tid];
  f32x4 bev = ((const f32x4*)be1)[tid];
  f32x4 y;
  y.x = (v.x - mean) * rst * gv.x + bev.x;
  y.y = (v.y - mean) * rst * gv.y + bev.y;
  y.z = (v.z - mean) * rst * gv.z + bev.z;
  y.w = (v.w - mean) * rst * gv.w + bev.w;
  ((f32x4*)xs)[tid] = y;
  __syncthreads();
  const int h = tid >> 4, c = tid & 15;
  const float* wb  = Wb + h * 1024;
  const float* wbg = Wbg + h * 1024;
  float p = 0.f, pg = 0.f;
  for (int i = c; i < 1024; i += 16) {
    float xv = xs[i];
    p += xv * wb[i];
    pg += xv * wbg[i];
  }
#pragma unroll
  for (int o = 1; o < 16; o <<= 1) { p += __shfl_xor(p, o); pg += __shfl_xor(pg, o); }
  if (c == 0) {
    float gate = 1.f / (1.f + expf(-(pg + bbg[h])));
    bg_tr[(((t >> 10) * 16 + h)) * 1024 + (t & 1023)] = (p + bb[h]) * gate;
  }
}

// ---------------------------------------------------------------------------
__global__ void scan_kernel(const float* __restrict__ bg_tr, const float* __restrict__ A,
                            const float* __restrict__ h0, float* __restrict__ hs,
                            float* __restrict__ lasth) {
  const int i = threadIdx.x;  // 0..63
  const int b = i >> 4, h = i & 15;
  const float delta = expf(A[h]);
  float hv = h0[b * 16 + h];
  const float* src = bg_tr + (size_t)i * 1024;
  for (int l = 0; l < 1024; l += 4) {
    f32x4 bx = *(const f32x4*)(src + l);
    hv = delta * hv + bx.x; hs[((size_t)(b << 10) + l + 0) * 16 + h] = hv;
    hv = delta * hv + bx.y; hs[((size_t)(b << 10) + l + 1) * 16 + h] = hv;
    hv = delta * hv + bx.z; hs[((size_t)(b << 10) + l + 2) * 16 + h] = hv;
    hv = delta * hv + bx.w; hs[((size_t)(b << 10) + l + 3) * 16 + h] = hv;
  }
  lasth[b * 16 + h] = hv;
}

// ---------------------------------------------------------------------------
// Pipelined 128x128x32 GEMM (C = A @ B^T), 4 waves x 64x64.
// 3-deep LDS rotation, counted vmcnt (never 0 in steady state), one raw
// s_barrier per K-step, bank-conflict swizzle (chunk ^= row&3, both sides).
// EPI: 0 = +bias -> f32 | 1 = gated (B1 stream) -> bf16 | 2 = gelu -> bf16
//      3 = +bias + residF -> f32 (outF/residF may alias, same-thread r->w)
template <bool GATED, int EPI>
__global__ __launch_bounds__(256, 2) void gemm_p(
    const u16* __restrict__ A, const u16* __restrict__ B0, const u16* __restrict__ B1,
    const float* __restrict__ bias0, const float* __restrict__ bias1,
    float* outF, u16* __restrict__ outB, const float* residF, int N, int K) {
  __shared__ u16 lds_a[3][128 * 32];
  __shared__ u16 lds_b[3][128 * 32];
  __shared__ u16 lds_g[GATED ? 3 : 1][GATED ? 128 * 32 : 8];

  const int tid = threadIdx.x;
  const int lane = tid & 63;
  const int w = tid >> 6;
  const int wm = w & 1, wn = w >> 1;
  const int r16 = lane & 15, kg = lane >> 4;
  const size_t rowA = (size_t)blockIdx.x * 128;
  const size_t rowB = (size_t)blockIdx.y * 128;

  f32x4 acc[4][4] = {};
  f32x4 accg[GATED ? 4 : 1][GATED ? 4 : 1] = {};

  auto stage = [&](int buf, int k0) {
#pragma unroll
    for (int s = 0; s < 2; ++s) {
      const int slot = s * 256 + tid;
      const int r = slot >> 2;
      const int cs = ((slot & 3) ^ (r & 3)) << 3;  // inverse-swizzled source chunk
      async_copy16(&lds_a[buf][slot * 8], A + (rowA + r) * K + k0 + cs);
      async_copy16(&lds_b[buf][slot * 8], B0 + (rowB + r) * K + k0 + cs);
      if constexpr (GATED)
        async_copy16(&lds_g[buf][slot * 8], B1 + (rowB + r) * K + k0 + cs);
    }
  };

  const int NT = K >> 5;
  stage(0, 0);
  stage(1, 32);
  int cur = 0;
  const int ca = (kg ^ (r16 & 3)) << 3;  // swizzled read chunk (bytes/2)

  for (int t = 0; t < NT; ++t) {
    // wait for tile t's loads only; keep the newest stage in flight
    if (t + 1 < NT) {
      if constexpr (GATED) asm volatile("s_waitcnt vmcnt(6)" ::: "memory");
      else                 asm volatile("s_waitcnt vmcnt(4)" ::: "memory");
    } else {
      asm volatile("s_waitcnt vmcnt(0)" ::: "memory");
    }
    __builtin_amdgcn_s_barrier();
    asm volatile("" ::: "memory");

    if (t + 2 < NT) stage((cur == 0) ? 2 : cur - 1, (t + 2) << 5);

    s16x8 af[4], bfr[4], gfr[GATED ? 4 : 1];
#pragma unroll
    for (int i = 0; i < 4; ++i)
      af[i] = *(const s16x8*)&lds_a[cur][(wm * 64 + i * 16 + r16) * 32 + ca];
#pragma unroll
    for (int i = 0; i < 4; ++i) {
      bfr[i] = *(const s16x8*)&lds_b[cur][(wn * 64 + i * 16 + r16) * 32 + ca];
      if constexpr (GATED)
        gfr[i] = *(const s16x8*)&lds_g[cur][(wn * 64 + i * 16 + r16) * 32 + ca];
    }
#pragma unroll
    for (int mi = 0; mi < 4; ++mi)
#pragma unroll
      for (int ni = 0; ni < 4; ++ni) {
        acc[mi][ni] = __builtin_amdgcn_mfma_f32_16x16x32_bf16(af[mi], bfr[ni], acc[mi][ni], 0, 0, 0);
        if constexpr (GATED)
          accg[mi][ni] =
              __builtin_amdgcn_mfma_f32_16x16x32_bf16(af[mi], gfr[ni], accg[mi][ni], 0, 0, 0);
      }
    cur = (cur == 2) ? 0 : cur + 1;
  }

  const int mbase = (int)rowA + wm * 64;
  const int nbase = (int)rowB + wn * 64;
#pragma unroll
  for (int mi = 0; mi < 4; ++mi) {
#pragma unroll
    for (int ni = 0; ni < 4; ++ni) {
      const int col = nbase + ni * 16 + r16;
      const float b0 = bias0[col];
      float b1 = 0.f;
      if constexpr (EPI == 1) b1 = bias1[col];
#pragma unroll
      for (int j = 0; j < 4; ++j) {
        const int rrow = mbase + mi * 16 + kg * 4 + j;
        const size_t idx = (size_t)rrow * N + col;
        const float v = acc[mi][ni][j] + b0;
        if constexpr (EPI == 0) {
          outF[idx] = v;
        } else if constexpr (EPI == 1) {
          const float vg = accg[mi][ni][j] + b1;
          outB[idx] = f2bf(v / (1.f + expf(-vg)));
        } else if constexpr (EPI == 2) {
          outB[idx] = f2bf(0.5f * v * (1.f + erff(v * 0.70710678118654752f)));
        } else {
          outF[idx] = v + residF[idx];
        }
      }
    }
  }
}

// ---------------------------------------------------------------------------
// contract: u[t,o] = bv[t,o] + u_in[t,o](=Dout) + sum_h hs[t,h]*cg[t,h*1024+o]
__global__ __launch_bounds__(256) void contract_kernel(
    const float* __restrict__ bv, const u16* __restrict__ cg,
    const float* __restrict__ hs, float* u) {
  const int t = blockIdx.x;
  const int tid = threadIdx.x;
  __shared__ float hsl[16];
  if (tid < 16) hsl[tid] = hs[(size_t)t * 16 + tid];
  __syncthreads();
  f32x4 acc = ((const f32x4*)(bv + (size_t)t * 1024))[tid];
  f32x4 dv = ((f32x4*)(u + (size_t)t * 1024))[tid];
  acc += dv;
  const u16* cgrow = cg + (size_t)t * 16384;
#pragma unroll
  for (int h = 0; h < 16; ++h) {
    float s = hsl[h];
    u16x4 cv = *(const u16x4*)(cgrow + h * 1024 + tid * 4);
    acc.x += s * bf2f(cv.x);
    acc.y += s * bf2f(cv.y);
    acc.z += s * bf2f(cv.z);
    acc.w += s * bf2f(cv.w);
  }
  ((f32x4*)(u + (size_t)t * 1024))[tid] = acc;
}

// ---------------------------------------------------------------------------
extern "C" void kernel_launch(void* const* d_in, const int* in_sizes, int n_in,
                              void* d_out, int out_size, void* d_ws, size_t ws_size,
                              hipStream_t stream) {
  const float* bv   = (const float*)d_in[0];
  const float* h0   = (const float*)d_in[1];
  const float* Aarr = (const float*)d_in[2];
  const float* Wb   = (const float*)d_in[3];
  const float* bb   = (const float*)d_in[4];
  const float* Wc   = (const float*)d_in[5];
  const float* bc   = (const float*)d_in[6];
  const float* Wd   = (const float*)d_in[7];
  const float* bd   = (const float*)d_in[8];
  const float* Wbg  = (const float*)d_in[9];
  const float* bbg  = (const float*)d_in[10];
  const float* Wcg  = (const float*)d_in[11];
  const float* bcg  = (const float*)d_in[12];
  const float* W1   = (const float*)d_in[13];
  const float* b1   = (const float*)d_in[14];
  const float* W2   = (const float*)d_in[15];
  const float* b2   = (const float*)d_in[16];
  const float* g1   = (const float*)d_in[17];
  const float* be1  = (const float*)d_in[18];
  const float* g2   = (const float*)d_in[19];
  const float* be2  = (const float*)d_in[20];

  float* out = (float*)d_out;
  float* out_lasth = out + (size_t)4096 * 1024;
  float* u_buf = out;  // u / Dout / y2-f32 live in d_out until FFN2 overwrites

  char* p = (char*)d_ws;
  auto take = [&](size_t bytes) -> char* {
    char* r = p;
    p += (bytes + 255) & ~(size_t)255;
    return r;
  };
  u16* wc_bf   = (u16*)take((size_t)16384 * 1024 * 2);  // 32 MB
  u16* wcg_bf  = (u16*)take((size_t)16384 * 1024 * 2);  // 32 MB
  u16* wd_bf   = (u16*)take((size_t)1024 * 1024 * 2);   //  2 MB
  u16* w1_bf   = (u16*)take((size_t)4096 * 1024 * 2);   //  8 MB
  u16* w2_bf   = (u16*)take((size_t)1024 * 4096 * 2);   //  8 MB
  u16* x_bf    = (u16*)take((size_t)4096 * 1024 * 2);   //  8 MB
  float* bg_tr = (float*)take((size_t)64 * 1024 * 4);   // .25 MB
  float* hs    = (float*)take((size_t)4096 * 16 * 4);   // .25 MB
  u16* cg_bf   = (u16*)take((size_t)4096 * 16384 * 2);  // 128 MB
  const size_t need = (size_t)(p - (char*)d_ws);        // ~218.5 MB (proven in R4)
  if (ws_size < need) return;

  // live only after the gated GEMM is done with the Wc/Wcg regions
  u16* f1_bf = wc_bf;   // 32 MB
  u16* y2_bf = wcg_bf;  //  8 MB

  // 1. weight conversions
  cvt_f32_bf16<<<16384, 256, 0, stream>>>(Wc, wc_bf, 16384 * 1024 / 4);
  cvt_f32_bf16<<<16384, 256, 0, stream>>>(Wcg, wcg_bf, 16384 * 1024 / 4);
  cvt_f32_bf16<<<1024, 256, 0, stream>>>(Wd, wd_bf, 1024 * 1024 / 4);
  cvt_f32_bf16<<<4096, 256, 0, stream>>>(W1, w1_bf, 4096 * 1024 / 4);
  cvt_f32_bf16<<<4096, 256, 0, stream>>>(W2, w2_bf, 1024 * 4096 / 4);

  // 2. LN1 -> x_bf16
  ln_kernel<<<4096, 256, 0, stream>>>(bv, g1, be1, x_bf, nullptr);

  // 3. gated B projection (own f32 LN, exact) -> bg_tr
  bproj_kernel<<<4096, 256, 0, stream>>>(bv, g1, be1, Wb, bb, Wbg, bbg, bg_tr);

  // 4. scan -> hs, last_h
  scan_kernel<<<1, 64, 0, stream>>>(bg_tr, Aarr, h0, hs, out_lasth);

  // 5a. gated C GEMM -> cg_bf (4096 x 16384)
  gemm_p<true, 1><<<dim3(32, 128), 256, 0, stream>>>(x_bf, wc_bf, wcg_bf, bc, bcg, nullptr,
                                                     cg_bf, nullptr, 16384, 1024);
  // 5b. Dout -> u_buf (d_out)
  gemm_p<false, 0><<<dim3(32, 8), 256, 0, stream>>>(x_bf, wd_bf, nullptr, bd, nullptr, u_buf,
                                                    nullptr, nullptr, 1024, 1024);
  // 5c. u = bv + Dout + sum_h hs*cg   (in-place on u_buf)
  contract_kernel<<<4096, 256, 0, stream>>>(bv, cg_bf, hs, u_buf);

  // 6. LN2 -> y2_bf16 (+ f32 y2 in-place into u_buf)
  ln_kernel<<<4096, 256, 0, stream>>>(u_buf, g2, be2, y2_bf, u_buf);

  // 7. FFN1 exact-erf GELU -> f1_bf (4096 x 4096)
  gemm_p<false, 2><<<dim3(32, 32), 256, 0, stream>>>(y2_bf, w1_bf, nullptr, b1, nullptr, nullptr,
                                                     f1_bf, nullptr, 4096, 1024);

  // 8. FFN2 + bias + residual(y2 f32) -> d_out
  gemm_p<false, 3><<<dim3(32, 8), 256, 0, stream>>>(f1_bf, w2_bf, nullptr, b2, nullptr, out,
                                                    nullptr, u_buf, 1024, 4096);
}